// Round 1
// baseline (399.416 us; speedup 1.0000x reference)
//
#include <hip/hip_runtime.h>

// FullAttention: O[b,l,h,d] = softmax_s( scale * Q[b,l,h,:]·K[b,s,h,:] ) @ V[b,s,h,:]
// B=4, L=S=2048, H=8, E=D=64, fp32 in/out, bf16 MFMA compute.
// R10: attn was latency-bound (MfmaUtil 22 + VALUBusy 27, occupancy 17% = 2 blocks/CU,
//      grid-limited not resource-limited). Two changes:
//      (1) splits=4 (fallback 2/1 on ws_size): grid 1024 -> 4 blocks/CU = 4 waves/SIMD.
//          launch_bounds(256,4) keeps VGPR <= 128 (was 124).
//      (2) XCD-pinning swizzle (attn + prep): bid&7 -> XCD, 4 (b,h) pairs per XCD
//          (2 MB KV bf16 fits the 4 MB per-XCD L2). Kills the ~40 MB of cross-XCD
//          KV re-fetch seen in FETCH_SIZE (73.8 MB vs ~34 MB compulsory).

#define B_ 4
#define L_ 2048
#define S_ 2048
#define H_ 8

#define NUMSZ (B_ * L_ * H_ * 64)   // 4194304 floats
#define LSZ (B_ * L_ * H_)          // 65536 floats
#define KVELEM (B_ * H_ * S_ * 64)  // 4194304 bf16 per buffer
#define TILE_ELEMS 2048             // one 32-s tile = 4 KB

typedef __attribute__((ext_vector_type(8))) __bf16 bf16x8;
typedef __attribute__((ext_vector_type(4))) __bf16 bf16x4;
typedef __attribute__((ext_vector_type(16))) float floatx16;

union BF4U { bf16x4 v; uint2 u; };
union BF8U { bf16x8 v; uint4 u; };

__device__ __forceinline__ void async_load16(const void* g, void* l) {
  __builtin_amdgcn_global_load_lds(
      (const __attribute__((address_space(1))) unsigned int*)g,
      (__attribute__((address_space(3))) unsigned int*)l, 16, 0, 0);
}

__device__ __forceinline__ bf16x8 cvt8(float4 a, float4 b) {
  bf16x8 r;
  r[0] = (__bf16)a.x; r[1] = (__bf16)a.y; r[2] = (__bf16)a.z; r[3] = (__bf16)a.w;
  r[4] = (__bf16)b.x; r[5] = (__bf16)b.y; r[6] = (__bf16)b.z; r[7] = (__bf16)b.w;
  return r;
}

// max-free softmax on one 32x32 score block + in-register C->B transform
// (validated R5-R7). Outputs the two PV B-fragments (s-chunks 0,1).
__device__ __forceinline__ void softmax_pb(const floatx16& sc, int h32, float& l,
                                           bf16x8& pB0v, bf16x8& pB1v) {
  BF4U pg[4];
#pragma unroll
  for (int g = 0; g < 4; ++g) {
    float p0 = __builtin_amdgcn_exp2f(sc[4 * g + 0]);
    float p1 = __builtin_amdgcn_exp2f(sc[4 * g + 1]);
    float p2 = __builtin_amdgcn_exp2f(sc[4 * g + 2]);
    float p3 = __builtin_amdgcn_exp2f(sc[4 * g + 3]);
    l += (p0 + p1) + (p2 + p3);
    pg[g].v = (bf16x4){(__bf16)p0, (__bf16)p1, (__bf16)p2, (__bf16)p3};
  }
  uint2 sendA = h32 ? pg[0].u : pg[1].u;
  uint2 sendB = h32 ? pg[2].u : pg[3].u;
  uint2 recvA, recvB;
  recvA.x = __shfl_xor((int)sendA.x, 32);
  recvA.y = __shfl_xor((int)sendA.y, 32);
  recvB.x = __shfl_xor((int)sendB.x, 32);
  recvB.y = __shfl_xor((int)sendB.y, 32);
  BF8U pB0, pB1;
  if (h32 == 0) {
    pB0.u = (uint4){pg[0].u.x, pg[0].u.y, recvA.x, recvA.y};
    pB1.u = (uint4){pg[2].u.x, pg[2].u.y, recvB.x, recvB.y};
  } else {
    pB0.u = (uint4){recvA.x, recvA.y, pg[1].u.x, pg[1].u.y};
    pB1.u = (uint4){recvB.x, recvB.y, pg[3].u.x, pg[3].u.y};
  }
  pB0v = pB0.v;
  pB1v = pB1.v;
}

// ---- pre-pass: K,V fp32 -> bf16 swizzled 4KB tiles.
// R10: XCD-pinned block decode — xcd = bid&7 owns (b,h) pairs [4*xcd, 4*xcd+3],
// matching attn's decode, so prep's L2 writes are attn's L2 hits.
__global__ __launch_bounds__(256) void prep_kernel(const float* __restrict__ K,
                                                   const float* __restrict__ V,
                                                   __bf16* __restrict__ Kb,
                                                   __bf16* __restrict__ Vb) {
  __shared__ float Vs[32 * 64];
  const int bid = blockIdx.x;
  const int xcd = bid & 7;
  const int idx = bid >> 3;            // 0..255 per XCD
  const int pair = xcd * 4 + (idx >> 6);  // (b*8+h), 4 pairs per XCD
  const int tile = idx & 63;
  const int h = pair & 7;
  const int b = pair >> 3;
  const int obid = pair * 64 + tile;   // output tile index (layout unchanged)
  const int s0 = tile * 32;
  const int i = threadIdx.x;

  {
    const int s = i >> 3, cp = i & 7;
    const int e0 = 8 * (cp ^ (s & 7));
    const float* src = K + (((size_t)(b * S_ + s0 + s) * H_ + h) * 64 + e0);
    float4 a = *(const float4*)src;
    float4 bb = *(const float4*)(src + 4);
    *(bf16x8*)(Kb + (size_t)obid * TILE_ELEMS + i * 8) = cvt8(a, bb);
  }
  {
    const int s = i >> 3, d0 = (i & 7) * 8;
    const float* src = V + (((size_t)(b * S_ + s0 + s) * H_ + h) * 64 + d0);
    float4 a = *(const float4*)src;
    float4 bb = *(const float4*)(src + 4);
    *(float4*)&Vs[s * 64 + d0] = a;
    *(float4*)&Vs[s * 64 + d0 + 4] = bb;
  }
  __syncthreads();
  {
    const int Ll = i >> 3, cp = i & 7;
    const int ci = cp ^ (Ll & 7);
    const int d = 2 * Ll + (ci >> 2);
    const int ch = ci & 3;
    BF8U o;
#pragma unroll
    for (int j = 0; j < 8; ++j) o.v[j] = (__bf16)Vs[(8 * ch + j) * 64 + d];
    *(bf16x8*)(Vb + (size_t)obid * TILE_ELEMS + i * 8) = o.v;
  }
}

__global__ __launch_bounds__(256, 4) void attn_kernel(const float* __restrict__ Q,
                                                      const __bf16* __restrict__ Kb,
                                                      const __bf16* __restrict__ Vb,
                                                      float* __restrict__ O,
                                                      float* __restrict__ num_ws,
                                                      float* __restrict__ l_ws,
                                                      int splits) {
  __shared__ __align__(16) __bf16 Kt[2][2 * TILE_ELEMS];  // dbuf, two 32-s sub-tiles
  __shared__ __align__(16) __bf16 Vt[2][2 * TILE_ELEMS];

  const int tid = threadIdx.x;
  const int lane = tid & 63;
  const int wave = tid >> 6;
  const int q32 = lane & 31;
  const int h32 = lane >> 5;

  // ---- R10 XCD-pinned decode: xcd = bid&7; each XCD owns 4 (b,h) pairs.
  // grid = 256*splits blocks; per XCD = 32*splits; per pair = 8*splits.
  const int bid = blockIdx.x;
  const int xcd = bid & 7;
  const int idx = bid >> 3;
  const int bs = 8 * splits;           // blocks per (b,h) pair
  const int pairl = idx / bs;          // 0..3
  const int sub = idx - pairl * bs;    // qb(3) | split
  const int pair = xcd * 4 + pairl;    // (b*8+h)
  const int qb = sub & 7;              // 8 q-blocks of 256 rows
  const int split = sub >> 3;
  const int h = pair & 7;
  const int b = pair >> 3;

  const int NT2 = (S_ / 32) / splits / 2;  // 64-s iterations
  const int tile0 = split * NT2 * 2;

  // ---- Q fragments for TWO q-groups (B-operand: n=q32, k=h32*8+j)
  const float qscale = 0.125f * 1.44269504088896340736f;
  const int qrow0 = qb * 256 + wave * 64 + q32;  // group g adds g*32
  bf16x8 qf[2][4];
#pragma unroll
  for (int g = 0; g < 2; ++g) {
    const float* qp = Q + ((size_t)(b * L_ + qrow0 + g * 32) * H_ + h) * 64;
#pragma unroll
    for (int c = 0; c < 4; ++c) {
      const float* p = qp + c * 16 + h32 * 8;
      float4 a = *(const float4*)p;
      float4 bb = *(const float4*)(p + 4);
      float t[8] = {a.x, a.y, a.z, a.w, bb.x, bb.y, bb.z, bb.w};
#pragma unroll
      for (int j = 0; j < 8; ++j) qf[g][c][j] = (__bf16)(t[j] * qscale);
    }
  }

  // ---- per-lane swizzled fragment offsets within a 4KB tile (R6 format)
  int koff[4];
#pragma unroll
  for (int c = 0; c < 4; ++c) koff[c] = (q32 * 8 + (((2 * c + h32) ^ (q32 & 7)))) * 8;
  int voff[2][2];
#pragma unroll
  for (int s2 = 0; s2 < 2; ++s2)
#pragma unroll
    for (int dt = 0; dt < 2; ++dt) {
      int dp = dt * 32 + q32;
      int Ll = dp >> 1;
      int ci = (dp & 1) * 4 + 2 * s2 + h32;
      voff[s2][dt] = (Ll * 8 + (ci ^ (Ll & 7))) * 8;
    }

  // ---- state: per-group l and O accumulators
  float l[2] = {0.f, 0.f};
  floatx16 ot[2][2];  // [q-group][d-tile]
#pragma unroll
  for (int g = 0; g < 2; ++g)
#pragma unroll
    for (int r = 0; r < 16; ++r) { ot[g][0][r] = 0.f; ot[g][1][r] = 0.f; }

  const __bf16* KbBH = Kb + (size_t)(pair * 64) * TILE_ELEMS;
  const __bf16* VbBH = Vb + (size_t)(pair * 64) * TILE_ELEMS;
  const int lin8 = (wave * 64 + lane) * 8;

  // ---- prologue: async-stage tiles (tile0, tile0+1) into buf0
#pragma unroll
  for (int st = 0; st < 2; ++st) {
    async_load16(KbBH + (size_t)(tile0 + st) * TILE_ELEMS + lin8,
                 &Kt[0][st * TILE_ELEMS + wave * 512]);
    async_load16(VbBH + (size_t)(tile0 + st) * TILE_ELEMS + lin8,
                 &Vt[0][st * TILE_ELEMS + wave * 512]);
  }

  for (int t = 0; t < NT2; ++t) {
    const int buf = t & 1;
    __syncthreads();  // buf staged; all reads of buf^1 complete

    if (t + 1 < NT2) {
#pragma unroll
      for (int st = 0; st < 2; ++st) {
        async_load16(KbBH + (size_t)(tile0 + 2 * (t + 1) + st) * TILE_ELEMS + lin8,
                     &Kt[buf ^ 1][st * TILE_ELEMS + wave * 512]);
        async_load16(VbBH + (size_t)(tile0 + 2 * (t + 1) + st) * TILE_ELEMS + lin8,
                     &Vt[buf ^ 1][st * TILE_ELEMS + wave * 512]);
      }
    }

#pragma unroll
    for (int sb = 0; sb < 2; ++sb) {
      const __bf16* Kbuf = &Kt[buf][sb * TILE_ELEMS];
      const __bf16* Vbuf = &Vt[buf][sb * TILE_ELEMS];

      // shared K fragments feed BOTH q-groups' QK
      bf16x8 kA[4];
#pragma unroll
      for (int c = 0; c < 4; ++c) kA[c] = *(const bf16x8*)&Kbuf[koff[c]];

      floatx16 sc0, sc1;
#pragma unroll
      for (int r = 0; r < 16; ++r) { sc0[r] = 0.f; sc1[r] = 0.f; }
#pragma unroll
      for (int c = 0; c < 4; ++c)
        sc0 = __builtin_amdgcn_mfma_f32_32x32x16_bf16(kA[c], qf[0][c], sc0, 0, 0, 0);
#pragma unroll
      for (int c = 0; c < 4; ++c)
        sc1 = __builtin_amdgcn_mfma_f32_32x32x16_bf16(kA[c], qf[1][c], sc1, 0, 0, 0);

      // group-0 softmax overlaps group-1 QK (independent); then vice versa
      bf16x8 p00, p01, p10, p11;
      softmax_pb(sc0, h32, l[0], p00, p01);
      softmax_pb(sc1, h32, l[1], p10, p11);

      // shared V fragments feed BOTH q-groups' PV
      bf16x8 vA[4];  // [s2*2 + dt]
      vA[0] = *(const bf16x8*)&Vbuf[voff[0][0]];
      vA[1] = *(const bf16x8*)&Vbuf[voff[0][1]];
      vA[2] = *(const bf16x8*)&Vbuf[voff[1][0]];
      vA[3] = *(const bf16x8*)&Vbuf[voff[1][1]];
      ot[0][0] = __builtin_amdgcn_mfma_f32_32x32x16_bf16(vA[0], p00, ot[0][0], 0, 0, 0);
      ot[0][1] = __builtin_amdgcn_mfma_f32_32x32x16_bf16(vA[1], p00, ot[0][1], 0, 0, 0);
      ot[1][0] = __builtin_amdgcn_mfma_f32_32x32x16_bf16(vA[0], p10, ot[1][0], 0, 0, 0);
      ot[1][1] = __builtin_amdgcn_mfma_f32_32x32x16_bf16(vA[1], p10, ot[1][1], 0, 0, 0);
      ot[0][0] = __builtin_amdgcn_mfma_f32_32x32x16_bf16(vA[2], p01, ot[0][0], 0, 0, 0);
      ot[0][1] = __builtin_amdgcn_mfma_f32_32x32x16_bf16(vA[3], p01, ot[0][1], 0, 0, 0);
      ot[1][0] = __builtin_amdgcn_mfma_f32_32x32x16_bf16(vA[2], p11, ot[1][0], 0, 0, 0);
      ot[1][1] = __builtin_amdgcn_mfma_f32_32x32x16_bf16(vA[3], p11, ot[1][1], 0, 0, 0);
    }
  }

  // ---- epilogue (per q-group)
#pragma unroll
  for (int g = 0; g < 2; ++g) {
    float lg = l[g] + __shfl_xor(l[g], 32);
    const int qrow = qrow0 + g * 32;
    if (splits == 1) {
      const float inv = 1.0f / lg;
      float* orow = O + ((size_t)(b * L_ + qrow) * H_ + h) * 64;
#pragma unroll
      for (int dt = 0; dt < 2; ++dt)
#pragma unroll
        for (int gg = 0; gg < 4; ++gg) {
          float4 v = {ot[g][dt][4 * gg + 0] * inv, ot[g][dt][4 * gg + 1] * inv,
                      ot[g][dt][4 * gg + 2] * inv, ot[g][dt][4 * gg + 3] * inv};
          *(float4*)(orow + dt * 32 + gg * 8 + h32 * 4) = v;
        }
    } else {
      float* nrow =
          num_ws + (size_t)split * NUMSZ + ((size_t)(b * L_ + qrow) * H_ + h) * 64;
#pragma unroll
      for (int dt = 0; dt < 2; ++dt)
#pragma unroll
        for (int gg = 0; gg < 4; ++gg) {
          float4 v = {ot[g][dt][4 * gg + 0], ot[g][dt][4 * gg + 1],
                      ot[g][dt][4 * gg + 2], ot[g][dt][4 * gg + 3]};
          *(float4*)(nrow + dt * 32 + gg * 8 + h32 * 4) = v;
        }
      if (h32 == 0)
        l_ws[(size_t)split * LSZ + (size_t)(b * L_ + qrow) * H_ + h] = lg;
    }
  }
}

__global__ __launch_bounds__(256) void combine_kernel(const float* __restrict__ num_ws,
                                                      const float* __restrict__ l_ws,
                                                      float* __restrict__ O, int splits) {
  const size_t i4 = ((size_t)blockIdx.x * 256 + threadIdx.x) * 4;
  float4 acc = {0.f, 0.f, 0.f, 0.f};
  float lt = 0.f;
  for (int s = 0; s < splits; ++s) {  // fixed order -> deterministic
    float4 v = *(const float4*)(num_ws + (size_t)s * NUMSZ + i4);
    acc.x += v.x; acc.y += v.y; acc.z += v.z; acc.w += v.w;
    lt += l_ws[(size_t)s * LSZ + (i4 >> 6)];
  }
  const float inv = 1.0f / lt;
  float4 o = {acc.x * inv, acc.y * inv, acc.z * inv, acc.w * inv};
  *(float4*)(O + i4) = o;
}

extern "C" void kernel_launch(void* const* d_in, const int* in_sizes, int n_in,
                              void* d_out, int out_size, void* d_ws, size_t ws_size,
                              hipStream_t stream) {
  const float* Q = (const float*)d_in[0];
  const float* K = (const float*)d_in[1];
  const float* V = (const float*)d_in[2];
  float* O = (float*)d_out;

  __bf16* Kb = (__bf16*)d_ws;
  __bf16* Vb = Kb + KVELEM;
  float* num_ws = (float*)(Vb + KVELEM);
  const size_t base = (size_t)2 * KVELEM * sizeof(__bf16);
  const size_t per_split = ((size_t)NUMSZ + (size_t)LSZ) * sizeof(float);
  int splits = 1;
  if (ws_size >= base + 4 * per_split) splits = 4;        // 1024 blocks = 4/CU
  else if (ws_size >= base + 2 * per_split) splits = 2;   // 512 blocks = 2/CU
  float* l_ws = num_ws + (size_t)splits * NUMSZ;

  prep_kernel<<<B_ * H_ * 64, 256, 0, stream>>>(K, V, Kb, Vb);
  dim3 grid(B_ * H_ * (L_ / 256) * splits);
  attn_kernel<<<grid, 256, 0, stream>>>(Q, Kb, Vb, O, num_ws, l_ws, splits);
  if (splits > 1) {
    combine_kernel<<<NUMSZ / 4 / 256, 256, 0, stream>>>(num_ws, l_ws, O, splits);
  }
}

// Round 2
// 150.841 us; speedup vs baseline: 2.6479x; 2.6479x over previous
//
#include <hip/hip_runtime.h>

// FullAttention: O[b,l,h,d] = softmax_s( scale * Q[b,l,h,:]·K[b,s,h,:] ) @ V[b,s,h,:]
// B=4, L=S=2048, H=8, E=D=64, fp32 in/out, bf16 MFMA compute.
// R11: R10's launch_bounds(256,4) forced a 64-VGPR allocation (HW occupancy steps
//      64/128/256) -> massive scratch spill (WRITE_SIZE 33->805 MB, attn 62->304us).
//      Revert to launch_bounds(256,2): compiler allocates ~124 VGPR (R9-verified),
//      which ALREADY permits 4 waves/SIMD (124 < 128). Occupancy comes from the
//      grid instead: keep splits=4 (1024 blocks = 4 blocks/CU) + R10's XCD-pinned
//      (b,h) decode so each XCD's 4 KV pairs (2 MB bf16) stay in its private L2.

#define B_ 4
#define L_ 2048
#define S_ 2048
#define H_ 8

#define NUMSZ (B_ * L_ * H_ * 64)   // 4194304 floats
#define LSZ (B_ * L_ * H_)          // 65536 floats
#define KVELEM (B_ * H_ * S_ * 64)  // 4194304 bf16 per buffer
#define TILE_ELEMS 2048             // one 32-s tile = 4 KB

typedef __attribute__((ext_vector_type(8))) __bf16 bf16x8;
typedef __attribute__((ext_vector_type(4))) __bf16 bf16x4;
typedef __attribute__((ext_vector_type(16))) float floatx16;

union BF4U { bf16x4 v; uint2 u; };
union BF8U { bf16x8 v; uint4 u; };

__device__ __forceinline__ void async_load16(const void* g, void* l) {
  __builtin_amdgcn_global_load_lds(
      (const __attribute__((address_space(1))) unsigned int*)g,
      (__attribute__((address_space(3))) unsigned int*)l, 16, 0, 0);
}

__device__ __forceinline__ bf16x8 cvt8(float4 a, float4 b) {
  bf16x8 r;
  r[0] = (__bf16)a.x; r[1] = (__bf16)a.y; r[2] = (__bf16)a.z; r[3] = (__bf16)a.w;
  r[4] = (__bf16)b.x; r[5] = (__bf16)b.y; r[6] = (__bf16)b.z; r[7] = (__bf16)b.w;
  return r;
}

// max-free softmax on one 32x32 score block + in-register C->B transform
// (validated R5-R7). Outputs the two PV B-fragments (s-chunks 0,1).
__device__ __forceinline__ void softmax_pb(const floatx16& sc, int h32, float& l,
                                           bf16x8& pB0v, bf16x8& pB1v) {
  BF4U pg[4];
#pragma unroll
  for (int g = 0; g < 4; ++g) {
    float p0 = __builtin_amdgcn_exp2f(sc[4 * g + 0]);
    float p1 = __builtin_amdgcn_exp2f(sc[4 * g + 1]);
    float p2 = __builtin_amdgcn_exp2f(sc[4 * g + 2]);
    float p3 = __builtin_amdgcn_exp2f(sc[4 * g + 3]);
    l += (p0 + p1) + (p2 + p3);
    pg[g].v = (bf16x4){(__bf16)p0, (__bf16)p1, (__bf16)p2, (__bf16)p3};
  }
  uint2 sendA = h32 ? pg[0].u : pg[1].u;
  uint2 sendB = h32 ? pg[2].u : pg[3].u;
  uint2 recvA, recvB;
  recvA.x = __shfl_xor((int)sendA.x, 32);
  recvA.y = __shfl_xor((int)sendA.y, 32);
  recvB.x = __shfl_xor((int)sendB.x, 32);
  recvB.y = __shfl_xor((int)sendB.y, 32);
  BF8U pB0, pB1;
  if (h32 == 0) {
    pB0.u = (uint4){pg[0].u.x, pg[0].u.y, recvA.x, recvA.y};
    pB1.u = (uint4){pg[2].u.x, pg[2].u.y, recvB.x, recvB.y};
  } else {
    pB0.u = (uint4){recvA.x, recvA.y, pg[1].u.x, pg[1].u.y};
    pB1.u = (uint4){recvB.x, recvB.y, pg[3].u.x, pg[3].u.y};
  }
  pB0v = pB0.v;
  pB1v = pB1.v;
}

// ---- pre-pass: K,V fp32 -> bf16 swizzled 4KB tiles.
// XCD-pinned block decode — xcd = bid&7 owns (b,h) pairs [4*xcd, 4*xcd+3],
// matching attn's decode, so prep's L2 writes are attn's L2 hits.
__global__ __launch_bounds__(256) void prep_kernel(const float* __restrict__ K,
                                                   const float* __restrict__ V,
                                                   __bf16* __restrict__ Kb,
                                                   __bf16* __restrict__ Vb) {
  __shared__ float Vs[32 * 64];
  const int bid = blockIdx.x;
  const int xcd = bid & 7;
  const int idx = bid >> 3;            // 0..255 per XCD
  const int pair = xcd * 4 + (idx >> 6);  // (b*8+h), 4 pairs per XCD
  const int tile = idx & 63;
  const int h = pair & 7;
  const int b = pair >> 3;
  const int obid = pair * 64 + tile;   // output tile index (layout unchanged)
  const int s0 = tile * 32;
  const int i = threadIdx.x;

  {
    const int s = i >> 3, cp = i & 7;
    const int e0 = 8 * (cp ^ (s & 7));
    const float* src = K + (((size_t)(b * S_ + s0 + s) * H_ + h) * 64 + e0);
    float4 a = *(const float4*)src;
    float4 bb = *(const float4*)(src + 4);
    *(bf16x8*)(Kb + (size_t)obid * TILE_ELEMS + i * 8) = cvt8(a, bb);
  }
  {
    const int s = i >> 3, d0 = (i & 7) * 8;
    const float* src = V + (((size_t)(b * S_ + s0 + s) * H_ + h) * 64 + d0);
    float4 a = *(const float4*)src;
    float4 bb = *(const float4*)(src + 4);
    *(float4*)&Vs[s * 64 + d0] = a;
    *(float4*)&Vs[s * 64 + d0 + 4] = bb;
  }
  __syncthreads();
  {
    const int Ll = i >> 3, cp = i & 7;
    const int ci = cp ^ (Ll & 7);
    const int d = 2 * Ll + (ci >> 2);
    const int ch = ci & 3;
    BF8U o;
#pragma unroll
    for (int j = 0; j < 8; ++j) o.v[j] = (__bf16)Vs[(8 * ch + j) * 64 + d];
    *(bf16x8*)(Vb + (size_t)obid * TILE_ELEMS + i * 8) = o.v;
  }
}

__global__ __launch_bounds__(256, 2) void attn_kernel(const float* __restrict__ Q,
                                                      const __bf16* __restrict__ Kb,
                                                      const __bf16* __restrict__ Vb,
                                                      float* __restrict__ O,
                                                      float* __restrict__ num_ws,
                                                      float* __restrict__ l_ws,
                                                      int splits) {
  __shared__ __align__(16) __bf16 Kt[2][2 * TILE_ELEMS];  // dbuf, two 32-s sub-tiles
  __shared__ __align__(16) __bf16 Vt[2][2 * TILE_ELEMS];

  const int tid = threadIdx.x;
  const int lane = tid & 63;
  const int wave = tid >> 6;
  const int q32 = lane & 31;
  const int h32 = lane >> 5;

  // ---- XCD-pinned decode: xcd = bid&7; each XCD owns 4 (b,h) pairs.
  // grid = 256*splits blocks; per XCD = 32*splits; per pair = 8*splits.
  const int bid = blockIdx.x;
  const int xcd = bid & 7;
  const int idx = bid >> 3;
  const int bs = 8 * splits;           // blocks per (b,h) pair
  const int pairl = idx / bs;          // 0..3
  const int sub = idx - pairl * bs;    // qb(3) | split
  const int pair = xcd * 4 + pairl;    // (b*8+h)
  const int qb = sub & 7;              // 8 q-blocks of 256 rows
  const int split = sub >> 3;
  const int h = pair & 7;
  const int b = pair >> 3;

  const int NT2 = (S_ / 32) / splits / 2;  // 64-s iterations
  const int tile0 = split * NT2 * 2;

  // ---- Q fragments for TWO q-groups (B-operand: n=q32, k=h32*8+j)
  const float qscale = 0.125f * 1.44269504088896340736f;
  const int qrow0 = qb * 256 + wave * 64 + q32;  // group g adds g*32
  bf16x8 qf[2][4];
#pragma unroll
  for (int g = 0; g < 2; ++g) {
    const float* qp = Q + ((size_t)(b * L_ + qrow0 + g * 32) * H_ + h) * 64;
#pragma unroll
    for (int c = 0; c < 4; ++c) {
      const float* p = qp + c * 16 + h32 * 8;
      float4 a = *(const float4*)p;
      float4 bb = *(const float4*)(p + 4);
      float t[8] = {a.x, a.y, a.z, a.w, bb.x, bb.y, bb.z, bb.w};
#pragma unroll
      for (int j = 0; j < 8; ++j) qf[g][c][j] = (__bf16)(t[j] * qscale);
    }
  }

  // ---- per-lane swizzled fragment offsets within a 4KB tile (R6 format)
  int koff[4];
#pragma unroll
  for (int c = 0; c < 4; ++c) koff[c] = (q32 * 8 + (((2 * c + h32) ^ (q32 & 7)))) * 8;
  int voff[2][2];
#pragma unroll
  for (int s2 = 0; s2 < 2; ++s2)
#pragma unroll
    for (int dt = 0; dt < 2; ++dt) {
      int dp = dt * 32 + q32;
      int Ll = dp >> 1;
      int ci = (dp & 1) * 4 + 2 * s2 + h32;
      voff[s2][dt] = (Ll * 8 + (ci ^ (Ll & 7))) * 8;
    }

  // ---- state: per-group l and O accumulators
  float l[2] = {0.f, 0.f};
  floatx16 ot[2][2];  // [q-group][d-tile]
#pragma unroll
  for (int g = 0; g < 2; ++g)
#pragma unroll
    for (int r = 0; r < 16; ++r) { ot[g][0][r] = 0.f; ot[g][1][r] = 0.f; }

  const __bf16* KbBH = Kb + (size_t)(pair * 64) * TILE_ELEMS;
  const __bf16* VbBH = Vb + (size_t)(pair * 64) * TILE_ELEMS;
  const int lin8 = (wave * 64 + lane) * 8;

  // ---- prologue: async-stage tiles (tile0, tile0+1) into buf0
#pragma unroll
  for (int st = 0; st < 2; ++st) {
    async_load16(KbBH + (size_t)(tile0 + st) * TILE_ELEMS + lin8,
                 &Kt[0][st * TILE_ELEMS + wave * 512]);
    async_load16(VbBH + (size_t)(tile0 + st) * TILE_ELEMS + lin8,
                 &Vt[0][st * TILE_ELEMS + wave * 512]);
  }

  for (int t = 0; t < NT2; ++t) {
    const int buf = t & 1;
    __syncthreads();  // buf staged; all reads of buf^1 complete

    if (t + 1 < NT2) {
#pragma unroll
      for (int st = 0; st < 2; ++st) {
        async_load16(KbBH + (size_t)(tile0 + 2 * (t + 1) + st) * TILE_ELEMS + lin8,
                     &Kt[buf ^ 1][st * TILE_ELEMS + wave * 512]);
        async_load16(VbBH + (size_t)(tile0 + 2 * (t + 1) + st) * TILE_ELEMS + lin8,
                     &Vt[buf ^ 1][st * TILE_ELEMS + wave * 512]);
      }
    }

#pragma unroll
    for (int sb = 0; sb < 2; ++sb) {
      const __bf16* Kbuf = &Kt[buf][sb * TILE_ELEMS];
      const __bf16* Vbuf = &Vt[buf][sb * TILE_ELEMS];

      // shared K fragments feed BOTH q-groups' QK
      bf16x8 kA[4];
#pragma unroll
      for (int c = 0; c < 4; ++c) kA[c] = *(const bf16x8*)&Kbuf[koff[c]];

      floatx16 sc0, sc1;
#pragma unroll
      for (int r = 0; r < 16; ++r) { sc0[r] = 0.f; sc1[r] = 0.f; }
#pragma unroll
      for (int c = 0; c < 4; ++c)
        sc0 = __builtin_amdgcn_mfma_f32_32x32x16_bf16(kA[c], qf[0][c], sc0, 0, 0, 0);
#pragma unroll
      for (int c = 0; c < 4; ++c)
        sc1 = __builtin_amdgcn_mfma_f32_32x32x16_bf16(kA[c], qf[1][c], sc1, 0, 0, 0);

      // group-0 softmax overlaps group-1 QK (independent); then vice versa
      bf16x8 p00, p01, p10, p11;
      softmax_pb(sc0, h32, l[0], p00, p01);
      softmax_pb(sc1, h32, l[1], p10, p11);

      // shared V fragments feed BOTH q-groups' PV
      bf16x8 vA[4];  // [s2*2 + dt]
      vA[0] = *(const bf16x8*)&Vbuf[voff[0][0]];
      vA[1] = *(const bf16x8*)&Vbuf[voff[0][1]];
      vA[2] = *(const bf16x8*)&Vbuf[voff[1][0]];
      vA[3] = *(const bf16x8*)&Vbuf[voff[1][1]];
      ot[0][0] = __builtin_amdgcn_mfma_f32_32x32x16_bf16(vA[0], p00, ot[0][0], 0, 0, 0);
      ot[0][1] = __builtin_amdgcn_mfma_f32_32x32x16_bf16(vA[1], p00, ot[0][1], 0, 0, 0);
      ot[1][0] = __builtin_amdgcn_mfma_f32_32x32x16_bf16(vA[0], p10, ot[1][0], 0, 0, 0);
      ot[1][1] = __builtin_amdgcn_mfma_f32_32x32x16_bf16(vA[1], p10, ot[1][1], 0, 0, 0);
      ot[0][0] = __builtin_amdgcn_mfma_f32_32x32x16_bf16(vA[2], p01, ot[0][0], 0, 0, 0);
      ot[0][1] = __builtin_amdgcn_mfma_f32_32x32x16_bf16(vA[3], p01, ot[0][1], 0, 0, 0);
      ot[1][0] = __builtin_amdgcn_mfma_f32_32x32x16_bf16(vA[2], p11, ot[1][0], 0, 0, 0);
      ot[1][1] = __builtin_amdgcn_mfma_f32_32x32x16_bf16(vA[3], p11, ot[1][1], 0, 0, 0);
    }
  }

  // ---- epilogue (per q-group)
#pragma unroll
  for (int g = 0; g < 2; ++g) {
    float lg = l[g] + __shfl_xor(l[g], 32);
    const int qrow = qrow0 + g * 32;
    if (splits == 1) {
      const float inv = 1.0f / lg;
      float* orow = O + ((size_t)(b * L_ + qrow) * H_ + h) * 64;
#pragma unroll
      for (int dt = 0; dt < 2; ++dt)
#pragma unroll
        for (int gg = 0; gg < 4; ++gg) {
          float4 v = {ot[g][dt][4 * gg + 0] * inv, ot[g][dt][4 * gg + 1] * inv,
                      ot[g][dt][4 * gg + 2] * inv, ot[g][dt][4 * gg + 3] * inv};
          *(float4*)(orow + dt * 32 + gg * 8 + h32 * 4) = v;
        }
    } else {
      float* nrow =
          num_ws + (size_t)split * NUMSZ + ((size_t)(b * L_ + qrow) * H_ + h) * 64;
#pragma unroll
      for (int dt = 0; dt < 2; ++dt)
#pragma unroll
        for (int gg = 0; gg < 4; ++gg) {
          float4 v = {ot[g][dt][4 * gg + 0], ot[g][dt][4 * gg + 1],
                      ot[g][dt][4 * gg + 2], ot[g][dt][4 * gg + 3]};
          *(float4*)(nrow + dt * 32 + gg * 8 + h32 * 4) = v;
        }
      if (h32 == 0)
        l_ws[(size_t)split * LSZ + (size_t)(b * L_ + qrow) * H_ + h] = lg;
    }
  }
}

__global__ __launch_bounds__(256) void combine_kernel(const float* __restrict__ num_ws,
                                                      const float* __restrict__ l_ws,
                                                      float* __restrict__ O, int splits) {
  const size_t i4 = ((size_t)blockIdx.x * 256 + threadIdx.x) * 4;
  float4 acc = {0.f, 0.f, 0.f, 0.f};
  float lt = 0.f;
  for (int s = 0; s < splits; ++s) {  // fixed order -> deterministic
    float4 v = *(const float4*)(num_ws + (size_t)s * NUMSZ + i4);
    acc.x += v.x; acc.y += v.y; acc.z += v.z; acc.w += v.w;
    lt += l_ws[(size_t)s * LSZ + (i4 >> 6)];
  }
  const float inv = 1.0f / lt;
  float4 o = {acc.x * inv, acc.y * inv, acc.z * inv, acc.w * inv};
  *(float4*)(O + i4) = o;
}

extern "C" void kernel_launch(void* const* d_in, const int* in_sizes, int n_in,
                              void* d_out, int out_size, void* d_ws, size_t ws_size,
                              hipStream_t stream) {
  const float* Q = (const float*)d_in[0];
  const float* K = (const float*)d_in[1];
  const float* V = (const float*)d_in[2];
  float* O = (float*)d_out;

  __bf16* Kb = (__bf16*)d_ws;
  __bf16* Vb = Kb + KVELEM;
  float* num_ws = (float*)(Vb + KVELEM);
  const size_t base = (size_t)2 * KVELEM * sizeof(__bf16);
  const size_t per_split = ((size_t)NUMSZ + (size_t)LSZ) * sizeof(float);
  int splits = 1;
  if (ws_size >= base + 4 * per_split) splits = 4;        // 1024 blocks = 4/CU
  else if (ws_size >= base + 2 * per_split) splits = 2;   // 512 blocks = 2/CU
  float* l_ws = num_ws + (size_t)splits * NUMSZ;

  prep_kernel<<<B_ * H_ * 64, 256, 0, stream>>>(K, V, Kb, Vb);
  dim3 grid(B_ * H_ * (L_ / 256) * splits);
  attn_kernel<<<grid, 256, 0, stream>>>(Q, Kb, Vb, O, num_ws, l_ws, splits);
  if (splits > 1) {
    combine_kernel<<<NUMSZ / 4 / 256, 256, 0, stream>>>(num_ws, l_ws, O, splits);
  }
}